// Round 5
// baseline (26.384 us; speedup 1.0000x reference)
//
#include <hip/hip_runtime.h>
#include <math.h>

#define FN 50
#define CARD 10000
#define NP 1225          // F*(F-1)/2
#define NTILE 77         // ceil(NP/16)
#define NPAD (NTILE*16)  // 1232
#define FSTRIDE 72       // halves per factor row (144 B)

typedef _Float16 half8 __attribute__((ext_vector_type(8)));
typedef __fp16 half2t __attribute__((ext_vector_type(2)));
typedef float floatx4 __attribute__((ext_vector_type(4)));

static __device__ __forceinline__ half2t h2max0(half2t v) {
  half2t r;
  r[0] = v[0] > (__fp16)0 ? v[0] : (__fp16)0;
  r[1] = v[1] > (__fp16)0 ? v[1] : (__fp16)0;
  return r;
}
static __device__ __forceinline__ float hdot2(half2t a, half2t b, float c) {
#if __has_builtin(__builtin_amdgcn_fdot2)
  return __builtin_amdgcn_fdot2(a, b, c, false);
#else
  return c + (float)a[0]*(float)b[0] + (float)a[1]*(float)b[1];
#endif
}

__global__ __launch_bounds__(256, 4)
void afm_kernel(const int* __restrict__ inp,
                const float* __restrict__ emb,
                const float* __restrict__ wlin,
                const float* __restrict__ blin,
                const float* __restrict__ W1,
                const float* __restrict__ b1,
                const float* __restrict__ W2,
                const float* __restrict__ b2,
                float* __restrict__ out)
{
  __shared__ __align__(16) _Float16 s_fac[FN][FSTRIDE];   // 7200 B
  __shared__ __align__(16) unsigned s_pij[NPAD];          // 4928 B (aliased to f32 logit in ph2)
  __shared__ __align__(16) half2t  s_lp[NPAD * 4];        // 19712 B: per-kq (logit, pool) f16 partials
  __shared__ float s_wl[FN];
  __shared__ float s_red[16];

  const int tid  = threadIdx.x;
  const int b    = blockIdx.x;
  const int lane = tid & 63;
  const int wave = tid >> 6;
  const int c    = lane & 15;   // fragment row/col index
  const int kq   = lane >> 4;   // k-quarter 0..3

  // ---- phase 0a: pair table (closed form) ----
  for (int p = tid; p < NPAD; p += 256) {
    int pp = p < NP ? p : NP - 1;
    int i = (int)((99.0f - sqrtf(9801.0f - 8.0f * (float)pp)) * 0.5f);
    if (i < 0) i = 0;
    while ((i + 1) * (98 - i) / 2 <= pp) ++i;
    while (i > 0 && i * (99 - i) / 2 > pp) --i;
    int j = pp - i * (99 - i) / 2 + i + 1;
    s_pij[p] = (unsigned)(i * (FSTRIDE * 2)) | ((unsigned)(j * (FSTRIDE * 2)) << 16);
  }

  // ---- phase 0b: factor gather f32 -> f16 LDS ----
  const int* inprow = inp + b * FN;
  for (int idx = tid; idx < FN * 16; idx += 256) {
    int f = idx >> 4, q = idx & 15;
    int flat = inprow[f] + f * CARD;
    floatx4 v = ((const floatx4*)emb)[(long)flat * 16 + q];
    _Float16* dst = &s_fac[f][q * 4];
    dst[0] = (_Float16)v[0]; dst[1] = (_Float16)v[1];
    dst[2] = (_Float16)v[2]; dst[3] = (_Float16)v[3];
  }
  if (tid < FN) {
    int flat = inprow[tid] + tid * CARD;
    s_wl[tid] = wlin[flat];
  }

  // ---- phase 0c: W1 fragments -> VGPRs (A = W1^T, m=a, k=d) ----
  // A[m=a][k=d]: a = mt*16 + c, d = ks*32 + kq*8 + j  ->  W1[d*64 + a]
  half8 w1f[2][4];
#pragma unroll
  for (int ks = 0; ks < 2; ++ks)
#pragma unroll
    for (int mt = 0; mt < 4; ++mt)
#pragma unroll
      for (int jj = 0; jj < 4; ++jj) {
        float x = W1[(ks * 32 + kq * 8 + 2 * jj)     * 64 + mt * 16 + c];
        float y = W1[(ks * 32 + kq * 8 + 2 * jj + 1) * 64 + mt * 16 + c];
        half2t hw = __builtin_amdgcn_cvt_pkrtz(x, y);
        w1f[ks][mt][2 * jj]     = (_Float16)hw[0];
        w1f[ks][mt][2 * jj + 1] = (_Float16)hw[1];
      }
  // b1 / W2 slices for this lane's 16 a-values (a = mt*16 + kq*4 + r), f16 packed
  half2t b1h[4][2], w2h[4][2];
#pragma unroll
  for (int mt = 0; mt < 4; ++mt) {
    floatx4 bv = ((const floatx4*)b1)[mt * 4 + kq];
    floatx4 wv = ((const floatx4*)W2)[mt * 4 + kq];
    b1h[mt][0] = __builtin_amdgcn_cvt_pkrtz(bv[0], bv[1]);
    b1h[mt][1] = __builtin_amdgcn_cvt_pkrtz(bv[2], bv[3]);
    w2h[mt][0] = __builtin_amdgcn_cvt_pkrtz(wv[0], wv[1]);
    w2h[mt][1] = __builtin_amdgcn_cvt_pkrtz(wv[2], wv[3]);
  }
  const half2t one2 = {(__fp16)1, (__fp16)1};

  __syncthreads();

  // ---- phase 1: pipelined pair tiles; 8 MFMA + fdot2 pooled + f16 epilogue ----
  const char* fbase = (const char*)&s_fac[0][0];
  const int koff = kq * 16;

  int t = wave;
  int pcur = t * 16 + c;
  {
    unsigned po = s_pij[pcur];
    int offi = (int)(po & 0xffffu) + koff;
    int offj = (int)(po >> 16) + koff;
    // fall through to loop with preloaded fragments
    half8 cvi0 = *(const half8*)(fbase + offi);
    half8 cvj0 = *(const half8*)(fbase + offj);
    half8 cvi1 = *(const half8*)(fbase + offi + 64);
    half8 cvj1 = *(const half8*)(fbase + offj + 64);

    while (true) {
      int tn = t + 4;
      int pn = tn * 16 + c; if (pn > NPAD - 1) pn = NPAD - 1;
      unsigned pon = s_pij[pn];               // prefetch pij (next)

      half8 pr0 = cvi0 * cvj0;                // inter, k-slice 0
      half8 pr1 = cvi1 * cvj1;                // k-slice 1

      floatx4 acc[4];
#pragma unroll
      for (int mt = 0; mt < 4; ++mt) {
        acc[mt] = __builtin_amdgcn_mfma_f32_16x16x32_f16(w1f[0][mt], pr0, (floatx4){0.f,0.f,0.f,0.f}, 0, 0, 0);
        acc[mt] = __builtin_amdgcn_mfma_f32_16x16x32_f16(w1f[1][mt], pr1, acc[mt], 0, 0, 0);
      }

      // pooled partial (this kq's 16 dims) via fdot2 on pr
      const half2t* pp0 = (const half2t*)&pr0;
      const half2t* pp1 = (const half2t*)&pr1;
      float pool = 0.f;
#pragma unroll
      for (int q = 0; q < 4; ++q) {
        pool = hdot2(pp0[q], one2, pool);
        pool = hdot2(pp1[q], one2, pool);
      }

      // prefetch next tile's fragments under the epilogue
      int offi_n = (int)(pon & 0xffffu) + koff;
      int offj_n = (int)(pon >> 16) + koff;
      cvi0 = *(const half8*)(fbase + offi_n);
      cvj0 = *(const half8*)(fbase + offj_n);
      cvi1 = *(const half8*)(fbase + offi_n + 64);
      cvj1 = *(const half8*)(fbase + offj_n + 64);

      // epilogue: bias + relu + W2 dot, f16-packed; no cross-lane
      float lg = 0.f;
#pragma unroll
      for (int mt = 0; mt < 4; ++mt) {
        half2t h0 = __builtin_amdgcn_cvt_pkrtz(acc[mt][0], acc[mt][1]);
        half2t h1 = __builtin_amdgcn_cvt_pkrtz(acc[mt][2], acc[mt][3]);
        h0 = h2max0(h0 + b1h[mt][0]);
        h1 = h2max0(h1 + b1h[mt][1]);
        lg = hdot2(h0, w2h[mt][0], lg);
        lg = hdot2(h1, w2h[mt][1], lg);
      }
      half2t lp;
      lp[0] = (__fp16)lg;
      lp[1] = (__fp16)pool;
      s_lp[pcur * 4 + kq] = lp;               // contiguous 256B/wave ds_write_b32

      t = tn;
      if (t >= NTILE) break;
      pcur = t * 16 + c;
    }
  }

  __syncthreads();

  // ---- phase 2: sum kq partials, softmax, weighted pool, line_out ----
  float* s_logit = (float*)s_pij;             // alias: pij dead now
  float* s_poolf = (float*)s_lp;              // reuse front as f32 pool? NO - overlap; use regs
  (void)s_poolf;
  float m = -1e30f;
  // first pass: logits to s_logit (alias of s_pij), track max; pool recomputed in 2nd pass
  for (int p = tid; p < NP; p += 256) {
    half2t v0 = s_lp[p * 4 + 0], v1 = s_lp[p * 4 + 1];
    half2t v2 = s_lp[p * 4 + 2], v3 = s_lp[p * 4 + 3];
    float lg = (float)v0[0] + (float)v1[0] + (float)v2[0] + (float)v3[0];
    s_logit[p] = lg;
    m = fmaxf(m, lg);
  }
#pragma unroll
  for (int o = 32; o; o >>= 1) m = fmaxf(m, __shfl_xor(m, o, 64));
  if (lane == 0) s_red[wave] = m;
  __syncthreads();
  m = fmaxf(fmaxf(s_red[0], s_red[1]), fmaxf(s_red[2], s_red[3]));
  float se = 0.f, spe = 0.f;
  for (int p = tid; p < NP; p += 256) {
    half2t v0 = s_lp[p * 4 + 0], v1 = s_lp[p * 4 + 1];
    half2t v2 = s_lp[p * 4 + 2], v3 = s_lp[p * 4 + 3];
    float pool = (float)v0[1] + (float)v1[1] + (float)v2[1] + (float)v3[1];
    float e = __expf(s_logit[p] - m);
    se += e;
    spe += e * pool;
  }
#pragma unroll
  for (int o = 32; o; o >>= 1) {
    se  += __shfl_xor(se, o, 64);
    spe += __shfl_xor(spe, o, 64);
  }
  if (lane == 0) { s_red[4 + wave] = se; s_red[8 + wave] = spe; }
  __syncthreads();
  if (tid == 0) {
    float line = blin[0];
#pragma unroll
    for (int f = 0; f < FN; ++f) line += s_wl[f];
    float SE  = s_red[4] + s_red[5] + s_red[6]  + s_red[7];
    float SPE = s_red[8] + s_red[9] + s_red[10] + s_red[11];
    out[b] = line + SPE / SE;
  }
}

extern "C" void kernel_launch(void* const* d_in, const int* in_sizes, int n_in,
                              void* d_out, int out_size, void* d_ws, size_t ws_size,
                              hipStream_t stream) {
  const int*   inp  = (const int*)d_in[0];
  const float* emb  = (const float*)d_in[1];
  const float* wlin = (const float*)d_in[2];
  const float* blin = (const float*)d_in[3];
  const float* W1   = (const float*)d_in[4];
  const float* b1   = (const float*)d_in[5];
  const float* W2   = (const float*)d_in[6];
  const float* b2   = (const float*)d_in[7];
  float* outp = (float*)d_out;
  const int B = in_sizes[0] / FN;
  afm_kernel<<<B, 256, 0, stream>>>(inp, emb, wlin, blin, W1, b1, W2, b2, outp);
}

// Round 6
// 24.952 us; speedup vs baseline: 1.0574x; 1.0574x over previous
//
#include <hip/hip_runtime.h>
#include <math.h>

#define FN 50
#define CARD 10000
#define NP 1225          // F*(F-1)/2
#define NTILE 77         // ceil(NP/16)
#define NPAD (NTILE*16)  // 1232
#define NCHUNK 39        // ceil(NTILE/2)
#define FSTRIDE 72       // halves per factor row (144 B)

typedef _Float16 half8 __attribute__((ext_vector_type(8)));
typedef __fp16 half2t __attribute__((ext_vector_type(2)));
typedef float floatx4 __attribute__((ext_vector_type(4)));

static __device__ __forceinline__ half2t h2max0(half2t v) {
  half2t r;
  r[0] = v[0] > (__fp16)0 ? v[0] : (__fp16)0;
  r[1] = v[1] > (__fp16)0 ? v[1] : (__fp16)0;
  return r;
}
static __device__ __forceinline__ float hdot2(half2t a, half2t b, float c) {
#if __has_builtin(__builtin_amdgcn_fdot2)
  return __builtin_amdgcn_fdot2(a, b, c, false);
#else
  return c + (float)a[0]*(float)b[0] + (float)a[1]*(float)b[1];
#endif
}

__global__ __launch_bounds__(256, 4)
void afm_kernel(const int* __restrict__ inp,
                const float* __restrict__ emb,
                const float* __restrict__ wlin,
                const float* __restrict__ blin,
                const float* __restrict__ W1,
                const float* __restrict__ b1,
                const float* __restrict__ W2,
                const float* __restrict__ b2,
                float* __restrict__ out)
{
  __shared__ __align__(16) _Float16 s_fac[FN][FSTRIDE];   // 7200 B
  __shared__ __align__(16) _Float16 s_w1[512 * 8];        // 8192 B, frag layout
  __shared__ __align__(16) unsigned s_pij[NPAD];          // 4928 B (aliased f32 logit in ph2)
  __shared__ __align__(16) __fp16 s_lg4[NPAD * 4];        // 9856 B, per-kq logit partials
  __shared__ float s_pool[NPAD];                          // 4928 B
  __shared__ float s_wl[FN];
  __shared__ float s_red[16];

  const int tid  = threadIdx.x;
  const int b    = blockIdx.x;
  const int lane = tid & 63;
  const int wave = tid >> 6;
  const int c    = lane & 15;
  const int kq   = lane >> 4;

  // ---- phase 0a: pair table (closed form + fixup) ----
  for (int p = tid; p < NPAD; p += 256) {
    int pp = p < NP ? p : NP - 1;
    int i = (int)((99.0f - sqrtf(9801.0f - 8.0f * (float)pp)) * 0.5f);
    if (i < 0) i = 0;
    while ((i + 1) * (98 - i) / 2 <= pp) ++i;
    while (i > 0 && i * (99 - i) / 2 > pp) --i;
    int j = pp - i * (99 - i) / 2 + i + 1;
    s_pij[p] = (unsigned)(i * (FSTRIDE * 2)) | ((unsigned)(j * (FSTRIDE * 2)) << 16);
  }

  // ---- phase 0b: factor gather f32 -> f16 LDS ----
  const int* inprow = inp + b * FN;
  for (int idx = tid; idx < FN * 16; idx += 256) {
    int f = idx >> 4, q = idx & 15;
    int flat = inprow[f] + f * CARD;
    floatx4 v = ((const floatx4*)emb)[(long)flat * 16 + q];
    _Float16* dst = &s_fac[f][q * 4];
    dst[0] = (_Float16)v[0]; dst[1] = (_Float16)v[1];
    dst[2] = (_Float16)v[2]; dst[3] = (_Float16)v[3];
  }
  if (tid < FN) {
    int flat = inprow[tid] + tid * CARD;
    s_wl[tid] = wlin[flat];
  }

  // ---- phase 0c: stage W1 into LDS in fragment layout ----
  for (int ch = tid; ch < 512; ch += 256) {
    int ks = ch >> 8, mt = (ch >> 6) & 3, ln = ch & 63;
    int cc = ln & 15, kk = ln >> 4;
    _Float16 tmp[8];
#pragma unroll
    for (int j = 0; j < 8; ++j)
      tmp[j] = (_Float16)W1[(ks * 32 + kk * 8 + j) * 64 + mt * 16 + cc];
    *(half8*)&s_w1[ch * 8] = *(const half8*)tmp;
  }

  // per-lane b1 / W2 slices (a = mt*16 + kq*4 + r), f16 packed
  half2t b1h[4][2], w2h[4][2];
#pragma unroll
  for (int mt = 0; mt < 4; ++mt) {
    floatx4 bv = ((const floatx4*)b1)[mt * 4 + kq];
    floatx4 wv = ((const floatx4*)W2)[mt * 4 + kq];
    b1h[mt][0] = __builtin_amdgcn_cvt_pkrtz(bv[0], bv[1]);
    b1h[mt][1] = __builtin_amdgcn_cvt_pkrtz(bv[2], bv[3]);
    w2h[mt][0] = __builtin_amdgcn_cvt_pkrtz(wv[0], wv[1]);
    w2h[mt][1] = __builtin_amdgcn_cvt_pkrtz(wv[2], wv[3]);
  }
  _Float16 onev = (c == 0) ? (_Float16)1 : (_Float16)0;
  half8 onesf = {onev, onev, onev, onev, onev, onev, onev, onev};

  __syncthreads();

  // ---- phase 1: 2-tile chunks, shared W1 reads, two interleaved chains ----
#define LDW1(ks, mt) (*(const half8*)&s_w1[(((ks) * 4 + (mt)) * 64 + lane) * 8])
  const char* fbase = (const char*)&s_fac[0][0];
  const int koff = kq * 16;
  const floatx4 zf4 = {0.f, 0.f, 0.f, 0.f};

  int k = wave;
  int tA = 2 * k, tB = 2 * k + 1; if (tB >= NTILE) tB = NTILE - 1;
  int pA = tA * 16 + c, pB = tB * 16 + c;
  unsigned poA = s_pij[pA], poB = s_pij[pB];
  int oiA = (int)(poA & 0xffffu) + koff, ojA = (int)(poA >> 16) + koff;
  int oiB = (int)(poB & 0xffffu) + koff, ojB = (int)(poB >> 16) + koff;
  half8 cviA0 = *(const half8*)(fbase + oiA);
  half8 cvjA0 = *(const half8*)(fbase + ojA);
  half8 cviA1 = *(const half8*)(fbase + oiA + 64);
  half8 cvjA1 = *(const half8*)(fbase + ojA + 64);
  half8 cviB0 = *(const half8*)(fbase + oiB);
  half8 cvjB0 = *(const half8*)(fbase + ojB);
  half8 cviB1 = *(const half8*)(fbase + oiB + 64);
  half8 cvjB1 = *(const half8*)(fbase + ojB + 64);

  while (true) {
    int kn = k + 4; if (kn > NCHUNK - 1) kn = NCHUNK - 1;
    int tAn = 2 * kn, tBn = 2 * kn + 1; if (tBn >= NTILE) tBn = NTILE - 1;
    int pAn = tAn * 16 + c, pBn = tBn * 16 + c;
    unsigned poAn = s_pij[pAn], poBn = s_pij[pBn];   // prefetch pij (next chunk)

    half8 prA0 = cviA0 * cvjA0;
    half8 prA1 = cviA1 * cvjA1;
    half8 prB0 = cviB0 * cvjB0;
    half8 prB1 = cviB1 * cvjB1;

    floatx4 accA[4], accB[4];
#pragma unroll
    for (int mt = 0; mt < 4; ++mt) {
      half8 w0 = LDW1(0, mt);
      accA[mt] = __builtin_amdgcn_mfma_f32_16x16x32_f16(w0, prA0, zf4, 0, 0, 0);
      accB[mt] = __builtin_amdgcn_mfma_f32_16x16x32_f16(w0, prB0, zf4, 0, 0, 0);
    }
#pragma unroll
    for (int mt = 0; mt < 4; ++mt) {
      half8 w1v = LDW1(1, mt);
      accA[mt] = __builtin_amdgcn_mfma_f32_16x16x32_f16(w1v, prA1, accA[mt], 0, 0, 0);
      accB[mt] = __builtin_amdgcn_mfma_f32_16x16x32_f16(w1v, prB1, accB[mt], 0, 0, 0);
    }
    floatx4 apA = __builtin_amdgcn_mfma_f32_16x16x32_f16(onesf, prA0, zf4, 0, 0, 0);
    apA = __builtin_amdgcn_mfma_f32_16x16x32_f16(onesf, prA1, apA, 0, 0, 0);
    float poolA = apA[0];
    floatx4 apB = __builtin_amdgcn_mfma_f32_16x16x32_f16(onesf, prB0, zf4, 0, 0, 0);
    apB = __builtin_amdgcn_mfma_f32_16x16x32_f16(onesf, prB1, apB, 0, 0, 0);
    float poolB = apB[0];

    // prefetch next chunk's factor fragments under the epilogues
    int oiAn = (int)(poAn & 0xffffu) + koff, ojAn = (int)(poAn >> 16) + koff;
    int oiBn = (int)(poBn & 0xffffu) + koff, ojBn = (int)(poBn >> 16) + koff;
    cviA0 = *(const half8*)(fbase + oiAn);
    cvjA0 = *(const half8*)(fbase + ojAn);
    cviA1 = *(const half8*)(fbase + oiAn + 64);
    cvjA1 = *(const half8*)(fbase + ojAn + 64);
    cviB0 = *(const half8*)(fbase + oiBn);
    cvjB0 = *(const half8*)(fbase + ojBn);
    cviB1 = *(const half8*)(fbase + oiBn + 64);
    cvjB1 = *(const half8*)(fbase + ojBn + 64);

    // epilogue A (retires accA), then B — independent chains
    float lgA = 0.f;
#pragma unroll
    for (int mt = 0; mt < 4; ++mt) {
      half2t h0 = __builtin_amdgcn_cvt_pkrtz(accA[mt][0], accA[mt][1]);
      half2t h1 = __builtin_amdgcn_cvt_pkrtz(accA[mt][2], accA[mt][3]);
      h0 = h2max0(h0 + b1h[mt][0]);
      h1 = h2max0(h1 + b1h[mt][1]);
      lgA = hdot2(h0, w2h[mt][0], lgA);
      lgA = hdot2(h1, w2h[mt][1], lgA);
    }
    float lgB = 0.f;
#pragma unroll
    for (int mt = 0; mt < 4; ++mt) {
      half2t h0 = __builtin_amdgcn_cvt_pkrtz(accB[mt][0], accB[mt][1]);
      half2t h1 = __builtin_amdgcn_cvt_pkrtz(accB[mt][2], accB[mt][3]);
      h0 = h2max0(h0 + b1h[mt][0]);
      h1 = h2max0(h1 + b1h[mt][1]);
      lgB = hdot2(h0, w2h[mt][0], lgB);
      lgB = hdot2(h1, w2h[mt][1], lgB);
    }
    s_lg4[pA * 4 + kq] = (__fp16)lgA;
    s_lg4[pB * 4 + kq] = (__fp16)lgB;
    if (kq == 0) { s_pool[pA] = poolA; s_pool[pB] = poolB; }

    k += 4;
    if (k >= NCHUNK) break;
    pA = pAn; pB = pBn;
  }
#undef LDW1

  __syncthreads();

  // ---- phase 2: sum kq partials, softmax, weighted pool, line_out ----
  float* s_logit = (float*)s_pij;             // alias: pij dead now
  float m = -1e30f;
  for (int p = tid; p < NP; p += 256) {
    const half2t* lp = (const half2t*)&s_lg4[p * 4];
    half2t sfh = lp[0] + lp[1];
    float lg = (float)sfh[0] + (float)sfh[1];
    s_logit[p] = lg;
    m = fmaxf(m, lg);
  }
#pragma unroll
  for (int o = 32; o; o >>= 1) m = fmaxf(m, __shfl_xor(m, o, 64));
  if (lane == 0) s_red[wave] = m;
  __syncthreads();
  m = fmaxf(fmaxf(s_red[0], s_red[1]), fmaxf(s_red[2], s_red[3]));
  float se = 0.f, spe = 0.f;
  for (int p = tid; p < NP; p += 256) {
    float e = __expf(s_logit[p] - m);
    se += e;
    spe += e * s_pool[p];
  }
#pragma unroll
  for (int o = 32; o; o >>= 1) {
    se  += __shfl_xor(se, o, 64);
    spe += __shfl_xor(spe, o, 64);
  }
  if (lane == 0) { s_red[4 + wave] = se; s_red[8 + wave] = spe; }
  __syncthreads();
  if (tid == 0) {
    float line = blin[0];
#pragma unroll
    for (int f = 0; f < FN; ++f) line += s_wl[f];
    float SE  = s_red[4] + s_red[5] + s_red[6]  + s_red[7];
    float SPE = s_red[8] + s_red[9] + s_red[10] + s_red[11];
    out[b] = line + SPE / SE;
  }
}

extern "C" void kernel_launch(void* const* d_in, const int* in_sizes, int n_in,
                              void* d_out, int out_size, void* d_ws, size_t ws_size,
                              hipStream_t stream) {
  const int*   inp  = (const int*)d_in[0];
  const float* emb  = (const float*)d_in[1];
  const float* wlin = (const float*)d_in[2];
  const float* blin = (const float*)d_in[3];
  const float* W1   = (const float*)d_in[4];
  const float* b1   = (const float*)d_in[5];
  const float* W2   = (const float*)d_in[6];
  const float* b2   = (const float*)d_in[7];
  float* outp = (float*)d_out;
  const int B = in_sizes[0] / FN;
  afm_kernel<<<B, 256, 0, stream>>>(inp, emb, wlin, blin, W1, b1, W2, b2, outp);
}